// Round 6
// baseline (2777.750 us; speedup 1.0000x reference)
//
#include <hip/hip_runtime.h>
#include <hip/hip_bf16.h>
#include <stdint.h>

// LPLRQuantizedLinear: B=8192 rows, N=M=4096, rank 64 (48 frozen + 16 ft).
// ALL float tensors are FP32 (per reference); Q_idxs int32; output FP32.
//
// Pipeline:
//   prep     : R_cat[64][4096] bf16 (ws), L_cat -> Wq[:, 4096:4160] bf16
//   decode   : Wq[:, :4096] = bf16(0.02 * grid[Q_idxs])      (f32 grid)
//   fwht_pre : h[:, :4096] = bf16(FWHT(x*SU)/64)             (radix-16 3-pass)
//   tgemm    : Tpart = h @ R_cat^T (k-split 4, fp32 partials)
//   tconv    : h[:, 4096:4160] = bf16(sum Tpart)
//   mgemm    : d_out = f32( h[8192,4160] @ Wq[4096,4160]^T ) -- 256^2, 2 blocks/CU
//   fwht_post: d_out = (FWHT(d_out)/64) * SV                 (radix-16 3-pass)
//
// mgemm history (measured):
//   v2b (ring4, 2ph, 4bars)  283us MfmaUtil 43%   v3 (1bar) 350  v4 (4ph/2K) 334
//   v5 (v2b + hoisted reads) 287 -- hoist changed NOTHING => limiter is that
//   1 block/CU keeps all 8 waves lockstep: read-drain windows leave the MFMA
//   pipe idle. v6: ring-2 (64 KiB LDS) -> 2 blocks/CU; cross-block overlap
//   fills MFMA during the other block's read/barrier windows.
// FWHT v2: was 8 LDS stages x 32 scalar b32 ops (issue-bound). Now radix-16:
//   3 reg passes (bits 0-3 / 4-7 / 8-11), skewed LDS addr = i + (i>>4)
//   (<=2-way banks, all passes), 80 LDS ops/thread, 2 syncs.

typedef __bf16 bf16;
typedef __bf16 bf16x8 __attribute__((ext_vector_type(8)));
typedef float f32x4 __attribute__((ext_vector_type(4)));

#define KE 4160
#define NN 4096
#define MM 4096
#define BB 8192

// ---------------- prep: build R_cat (bf16) and L columns of Wq ----------------
__global__ void prep_kernel(const float* __restrict__ Lft, const float* __restrict__ Rft,
                            const float* __restrict__ Lres, const float* __restrict__ Rres,
                            bf16* __restrict__ Rcat, bf16* __restrict__ Wq) {
  int tid = blockIdx.x * 256 + threadIdx.x;   // 524288 total
  if (tid < 64 * 4096) {
    int r = tid >> 12, n = tid & 4095;
    float v = (r < 48) ? Rres[r * 4096 + n] : Rft[(r - 48) * 4096 + n];
    Rcat[tid] = (bf16)v;
  } else {
    int t2 = tid - 64 * 4096;
    int m = t2 >> 6, r = t2 & 63;
    float v = (r < 48) ? Lres[m * 48 + r] : Lft[m * 16 + (r - 48)];
    Wq[(size_t)m * KE + 4096 + r] = (bf16)v;
  }
}

// ---------------- decode: Wq[:, :4096] = bf16(0.02*grid[Q_idxs]) ----------------
__global__ void decode_kernel(const int* __restrict__ qidx, const float* __restrict__ grid,
                              bf16* __restrict__ Wq) {
  int tid = blockIdx.x * 256 + threadIdx.x;   // 4096*512 = 2M
  int m = tid >> 9, g = tid & 511;
  uint32_t idx = (uint32_t)qidx[tid];
  const float4* gp = (const float4*)(grid + (size_t)idx * 8);
  float4 w0 = gp[0], w1 = gp[1];
  bf16x8 o;
  o[0] = (bf16)(w0.x * 0.02f); o[1] = (bf16)(w0.y * 0.02f);
  o[2] = (bf16)(w0.z * 0.02f); o[3] = (bf16)(w0.w * 0.02f);
  o[4] = (bf16)(w1.x * 0.02f); o[5] = (bf16)(w1.y * 0.02f);
  o[6] = (bf16)(w1.z * 0.02f); o[7] = (bf16)(w1.w * 0.02f);
  *(bf16x8*)(Wq + (size_t)m * KE + g * 8) = o;
}

// 4-stage (16-point) FWHT on a register array
#define FWHT16(v) \
  _Pragma("unroll") \
  for (int s_ = 1; s_ < 16; s_ <<= 1) { \
    _Pragma("unroll") \
    for (int i_ = 0; i_ < 16; ++i_) { \
      if (!(i_ & s_)) { float a_ = v[i_], b_ = v[i_ + s_]; v[i_] = a_ + b_; v[i_ + s_] = a_ - b_; } \
    } \
  }

// ---------------- FWHT-4096 radix-16 3-pass, f32 in -> bf16 out ----------------
// Skewed LDS: element a stored at buf[a + (a>>4)] (4352 floats). Bank spread
// verified <=2-way for all three access patterns (16t+i, base+16k, t+256k).
__global__ void fwht_pre_kernel(const float* __restrict__ src,
                                bf16* __restrict__ dst,
                                const float* __restrict__ SU) {
  __shared__ float buf[4352];
  const int row = blockIdx.x, t = threadIdx.x;
  const float4* sp = (const float4*)(src + (size_t)row * NN + t * 16);
  const float4* su = (const float4*)(SU + t * 16);
  float v[16];
#pragma unroll
  for (int q = 0; q < 4; ++q) {
    float4 a = sp[q], s = su[q];
    v[q * 4 + 0] = a.x * s.x; v[q * 4 + 1] = a.y * s.y;
    v[q * 4 + 2] = a.z * s.z; v[q * 4 + 3] = a.w * s.w;
  }
  FWHT16(v)                                    // bits 0-3 (elements 16t..16t+15)
#pragma unroll
  for (int i = 0; i < 16; ++i) buf[17 * t + i] = v[i];   // a=16t+i -> a+(a>>4)=17t+i
  __syncthreads();
  const int base = ((t >> 4) << 8) | (t & 15);
#pragma unroll
  for (int k = 0; k < 16; ++k) { int a = base + (k << 4); v[k] = buf[a + (a >> 4)]; }
  FWHT16(v)                                    // bits 4-7 (stride-16 set)
#pragma unroll
  for (int k = 0; k < 16; ++k) { int a = base + (k << 4); buf[a + (a >> 4)] = v[k]; }
  __syncthreads();
#pragma unroll
  for (int k = 0; k < 16; ++k) { int a = t + (k << 8); v[k] = buf[a + (a >> 4)]; }
  FWHT16(v)                                    // bits 8-11 (stride-256 set)
  bf16* dp = dst + (size_t)row * KE;
#pragma unroll
  for (int k = 0; k < 16; ++k) dp[t + (k << 8)] = (bf16)(v[k] * 0.015625f);
}

// ---------------- FWHT-4096 radix-16 3-pass, f32 in-place (post, *SV) ----------------
__global__ void fwht_post_kernel(float* __restrict__ data, const float* __restrict__ SV) {
  __shared__ float buf[4352];
  const int row = blockIdx.x, t = threadIdx.x;
  const float4* dp = (const float4*)(data + (size_t)row * MM + t * 16);
  float v[16];
#pragma unroll
  for (int q = 0; q < 4; ++q) {
    float4 a = dp[q];
    v[q * 4 + 0] = a.x; v[q * 4 + 1] = a.y; v[q * 4 + 2] = a.z; v[q * 4 + 3] = a.w;
  }
  FWHT16(v)
#pragma unroll
  for (int i = 0; i < 16; ++i) buf[17 * t + i] = v[i];
  __syncthreads();   // also orders: all initial global reads consumed before any write below
  const int base = ((t >> 4) << 8) | (t & 15);
#pragma unroll
  for (int k = 0; k < 16; ++k) { int a = base + (k << 4); v[k] = buf[a + (a >> 4)]; }
  FWHT16(v)
#pragma unroll
  for (int k = 0; k < 16; ++k) { int a = base + (k << 4); buf[a + (a >> 4)] = v[k]; }
  __syncthreads();
#pragma unroll
  for (int k = 0; k < 16; ++k) { int a = t + (k << 8); v[k] = buf[a + (a >> 4)]; }
  FWHT16(v)
  float* op = data + (size_t)row * MM;
#pragma unroll
  for (int k = 0; k < 16; ++k) { int a = t + (k << 8); op[a] = v[k] * 0.015625f * SV[a]; }
}

// ---------------- tgemm: Tpart[split] = h @ R_cat^T ----------------
__global__ void __launch_bounds__(256) tgemm_kernel(const bf16* __restrict__ A,
                                                    const bf16* __restrict__ Bm,
                                                    float* __restrict__ Tpart) {
  __shared__ bf16 lA[128 * 32];
  __shared__ bf16 lB[64 * 32];
  const int t = threadIdx.x, w = t >> 6, l = t & 63;
  const int bmBlk = blockIdx.x;   // 64 row blocks
  const int split = blockIdx.y;   // 4 k-splits
  const int wm = w >> 1, wn = w & 1;
  f32x4 acc[4][2] = {};
  const int arow = t >> 1, acol = (t & 1) * 16;            // A staging: 128 rows x 32
  const bf16* pa = A + (size_t)(bmBlk * 128 + arow) * KE + acol;
  const int brow = (t & 127) >> 1, bcol = acol;            // B staging: 64 rows x 32
  const bf16* pb = Bm + (size_t)brow * 4096 + bcol;
  const int fr = l & 15, fk = (l >> 4) * 8;
  for (int kt = 0; kt < 32; ++kt) {
    const int k0 = (split * 32 + kt) * 32;
    bf16x8 a0 = *(const bf16x8*)(pa + k0);
    bf16x8 a1 = *(const bf16x8*)(pa + k0 + 8);
    *(bf16x8*)&lA[arow * 32 + acol] = a0;
    *(bf16x8*)&lA[arow * 32 + acol + 8] = a1;
    if (t < 128) {
      bf16x8 b0 = *(const bf16x8*)(pb + k0);
      bf16x8 b1 = *(const bf16x8*)(pb + k0 + 8);
      *(bf16x8*)&lB[brow * 32 + bcol] = b0;
      *(bf16x8*)&lB[brow * 32 + bcol + 8] = b1;
    }
    __syncthreads();
    bf16x8 af[4], bfr[2];
#pragma unroll
    for (int i = 0; i < 4; ++i) af[i] = *(const bf16x8*)&lA[(wm * 64 + i * 16 + fr) * 32 + fk];
#pragma unroll
    for (int i = 0; i < 2; ++i) bfr[i] = *(const bf16x8*)&lB[(wn * 32 + i * 16 + fr) * 32 + fk];
#pragma unroll
    for (int mi = 0; mi < 4; ++mi)
#pragma unroll
      for (int ni = 0; ni < 2; ++ni)
        acc[mi][ni] = __builtin_amdgcn_mfma_f32_16x16x32_bf16(af[mi], bfr[ni], acc[mi][ni], 0, 0, 0);
    __syncthreads();
  }
  float* out = Tpart + (size_t)split * BB * 64;
  const int orow = bmBlk * 128 + wm * 64 + (l >> 4) * 4;
  const int ocol = wn * 32 + (l & 15);
#pragma unroll
  for (int mi = 0; mi < 4; ++mi)
#pragma unroll
    for (int ni = 0; ni < 2; ++ni)
#pragma unroll
      for (int r = 0; r < 4; ++r)
        out[(size_t)(orow + mi * 16 + r) * 64 + ocol + ni * 16] = acc[mi][ni][r];
}

__global__ void tconv_kernel(const float* __restrict__ Tpart, bf16* __restrict__ h) {
  int i = blockIdx.x * 256 + threadIdx.x;   // 8192*64
  float s = Tpart[i] + Tpart[i + BB * 64] + Tpart[i + 2 * BB * 64] + Tpart[i + 3 * BB * 64];
  int row = i >> 6, c = i & 63;
  h[(size_t)row * KE + 4096 + c] = (bf16)s;
}

// ---------------- mgemm v6: 256^2, ring-2 slots, 2 blocks/CU ----------------
// C[8192,4096] f32 = A[8192,4160] @ B[4096,4160]^T, bf16 MFMA.
// 2 K-step slots (BK=32): sA/sB [2][256*32] bf16 = 32 KiB each, 64 KiB total
// -> 2 blocks/CU (the v5 limiter was 1 block/CU wave-lockstep).
// T2 swizzle unchanged (measured 0 conflicts). Per iter j:
//   stage K(j+1) -> slot (j+1)&1   (safe: K(j-1) reads lgkm-drained via MFMA
//                                   consumption before iter j-1's final bar)
//   read 12 frags from slot j&1; bar; MFMA-A; bar; MFMA-B;
//   vmcnt(0) (waits loads issued a full iter ago); bar.

__device__ __forceinline__ void gload16(const void* g, void* l) {
  __builtin_amdgcn_global_load_lds(
      (const __attribute__((address_space(1))) void*)g,
      (__attribute__((address_space(3))) void*)l, 16, 0, 0);
}

__device__ __forceinline__ void bar() {
  asm volatile("" ::: "memory");
  __builtin_amdgcn_s_barrier();
  asm volatile("" ::: "memory");
}

__global__ void __launch_bounds__(512, 4) mgemm_kernel(const bf16* __restrict__ A,
                                                       const bf16* __restrict__ B,
                                                       float* __restrict__ C) {
  __shared__ alignas(16) char sA[32768];   // 2 slots x 256x32 bf16
  __shared__ alignas(16) char sB[32768];
  const int t = threadIdx.x;
  const int w = t >> 6, l = t & 63;
  const int wm = w >> 2, wn = w & 3;           // 2M x 4N waves, per-wave 128x64
  // bijective XCD swizzle (512 blocks, 512%8==0): each XCD gets 4 bm x 16 bn
  const int bid = blockIdx.x;
  const int swzb = (bid & 7) * 64 + (bid >> 3);
  const int bm = swzb >> 4, bn = swzb & 15;

  // ---- staging precompute: chunk c = w*2+j covers LDS bytes [c*1024, +1024)
  const int c0 = w * 2, c1 = w * 2 + 1;
  const int lb0 = c0 * 1024 + l * 16;
  const int lb1 = c1 * 1024 + l * 16;
  const int sb0 = lb0 ^ (((lb0 >> 7) & 3) << 4);
  const int sb1 = lb1 ^ (((lb1 >> 7) & 3) << 4);
  const char* gA0 = (const char*)(A + (size_t)(bm * 256 + (sb0 >> 6)) * KE) + (sb0 & 63);
  const char* gA1 = (const char*)(A + (size_t)(bm * 256 + (sb1 >> 6)) * KE) + (sb1 & 63);
  const char* gB0 = (const char*)(B + (size_t)(bn * 256 + (sb0 >> 6)) * KE) + (sb0 & 63);
  const char* gB1 = (const char*)(B + (size_t)(bn * 256 + (sb1 >> 6)) * KE) + (sb1 & 63);

  // ---- fragment ds_read byte offsets (within a 16 KiB slot), swizzled
  const int fr = l & 15, fkb = (l >> 4) * 16;
  int offA[8], offB[4];
#pragma unroll
  for (int mi = 0; mi < 8; ++mi) {
    int lb = (wm * 128 + mi * 16 + fr) * 64 + fkb;
    offA[mi] = lb ^ (((lb >> 7) & 3) << 4);
  }
#pragma unroll
  for (int ni = 0; ni < 4; ++ni) {
    int lb = (wn * 64 + ni * 16 + fr) * 64 + fkb;
    offB[ni] = lb ^ (((lb >> 7) & 3) << 4);
  }

  f32x4 acc[8][4] = {};

  // ---- prologue: stage K0 -> slot 0; drain; bar
  gload16(gA0, &sA[c0 * 1024]);
  gload16(gA1, &sA[c1 * 1024]);
  gload16(gB0, &sB[c0 * 1024]);
  gload16(gB1, &sB[c1 * 1024]);
  asm volatile("s_waitcnt vmcnt(0)" ::: "memory");
  __builtin_amdgcn_sched_barrier(0);
  bar();

  // ---- main loop: 130 K-steps of 32
  for (int j = 0; j < 130; ++j) {
    const int cur = (j & 1) << 14;
    const int nxt = ((j + 1) & 1) << 14;
    const size_t ko = (size_t)(j + 1) << 6;
    if (j <= 128) {
      gload16(gA0 + ko, &sA[nxt + c0 * 1024]);
      gload16(gA1 + ko, &sA[nxt + c1 * 1024]);
      gload16(gB0 + ko, &sB[nxt + c0 * 1024]);
      gload16(gB1 + ko, &sB[nxt + c1 * 1024]);
    }
    bf16x8 af[4], af2[4], bv[4];
#pragma unroll
    for (int mi = 0; mi < 4; ++mi) af[mi] = *(const bf16x8*)&sA[cur + offA[mi]];
#pragma unroll
    for (int ni = 0; ni < 4; ++ni) bv[ni] = *(const bf16x8*)&sB[cur + offB[ni]];
#pragma unroll
    for (int mi = 0; mi < 4; ++mi) af2[mi] = *(const bf16x8*)&sA[cur + offA[4 + mi]];
    bar();
    __builtin_amdgcn_s_setprio(1);
#pragma unroll
    for (int mi = 0; mi < 4; ++mi)
#pragma unroll
      for (int ni = 0; ni < 4; ++ni)
        acc[mi][ni] = __builtin_amdgcn_mfma_f32_16x16x32_bf16(af[mi], bv[ni], acc[mi][ni], 0, 0, 0);
    __builtin_amdgcn_s_setprio(0);
    bar();
    __builtin_amdgcn_s_setprio(1);
#pragma unroll
    for (int mi = 0; mi < 4; ++mi)
#pragma unroll
      for (int ni = 0; ni < 4; ++ni)
        acc[4 + mi][ni] = __builtin_amdgcn_mfma_f32_16x16x32_bf16(af2[mi], bv[ni], acc[4 + mi][ni], 0, 0, 0);
    __builtin_amdgcn_s_setprio(0);
    if (j <= 128) {
      asm volatile("s_waitcnt vmcnt(0)" ::: "memory");   // K(j+1) landed (issued 1 iter ago)
      __builtin_amdgcn_sched_barrier(0);
    }
    bar();
  }

  // ---- epilogue: C write
  const int orow = bm * 256 + wm * 128 + ((l >> 4) << 2);
  const int ocol = bn * 256 + wn * 64 + (l & 15);
#pragma unroll
  for (int mi = 0; mi < 8; ++mi)
#pragma unroll
    for (int ni = 0; ni < 4; ++ni)
#pragma unroll
      for (int r = 0; r < 4; ++r)
        C[(size_t)(orow + mi * 16 + r) * MM + ocol + ni * 16] = acc[mi][ni][r];
}

extern "C" void kernel_launch(void* const* d_in, const int* in_sizes, int n_in,
                              void* d_out, int out_size, void* d_ws, size_t ws_size,
                              hipStream_t stream) {
  const float* x    = (const float*)d_in[0];
  const float* SU   = (const float*)d_in[1];
  const float* SV   = (const float*)d_in[2];
  const float* grid = (const float*)d_in[3];
  const float* Lft  = (const float*)d_in[4];
  const float* Rft  = (const float*)d_in[5];
  const float* Lres = (const float*)d_in[6];
  const float* Rres = (const float*)d_in[7];
  const int*   qidx = (const int*)d_in[10];
  float* out = (float*)d_out;

  char* ws = (char*)d_ws;
  bf16*  h     = (bf16*)ws;                                   // 8192*4160*2 = 68,157,440
  bf16*  Wq    = (bf16*)(ws + 68157440);                      // 4096*4160*2 = 34,078,720
  bf16*  Rcat  = (bf16*)(ws + 68157440 + 34078720);           // 64*4096*2   =    524,288
  float* Tpart = (float*)(ws + 68157440 + 34078720 + 524288); // 4*8192*64*4 =  8,388,608

  prep_kernel<<<2048, 256, 0, stream>>>(Lft, Rft, Lres, Rres, Rcat, Wq);
  decode_kernel<<<8192, 256, 0, stream>>>(qidx, grid, Wq);
  fwht_pre_kernel<<<8192, 256, 0, stream>>>(x, h, SU);
  tgemm_kernel<<<dim3(64, 4), 256, 0, stream>>>(h, Rcat, Tpart);
  tconv_kernel<<<2048, 256, 0, stream>>>(Tpart, h);
  mgemm_kernel<<<512, 512, 0, stream>>>(h, Wq, out);
  fwht_post_kernel<<<8192, 256, 0, stream>>>(out, SV);
}

// Round 7
// 626.492 us; speedup vs baseline: 4.4338x; 4.4338x over previous
//
#include <hip/hip_runtime.h>
#include <hip/hip_bf16.h>
#include <stdint.h>

// LPLRQuantizedLinear: B=8192 rows, N=M=4096, rank 64 (48 frozen + 16 ft).
// ALL float tensors are FP32 (per reference); Q_idxs int32; output FP32.
//
// Pipeline:
//   prep     : R_cat[64][4096] bf16 (ws), L_cat -> Wq[:, 4096:4160] bf16
//   decode   : Wq[:, :4096] = bf16(0.02 * grid[Q_idxs])      (f32 grid)
//   fwht_pre : h[:, :4096] = bf16(FWHT(x*SU)/64)             (radix-16 3-pass)
//   tgemm    : Tpart = h @ R_cat^T (k-split 4, fp32 partials)
//   tconv    : h[:, 4096:4160] = bf16(sum Tpart)
//   mgemm    : d_out = f32( h[8192,4160] @ Wq[4096,4160]^T ) -- v7: BK=64 m201-style
//   fwht_post: d_out = (FWHT(d_out)/64) * SV                 (radix-16 3-pass)
//
// mgemm history (measured):
//   v2b ring4 2ph: 283us MfmaUtil 43%  | v3 1bar: 350 | v4 4ph/2K: 334
//   v5 hoisted reads: 287              | v6 ring2 2blk/CU: 2438 (VGPR 64 ->
//   acc SPILLED; launch_bounds(512,4) caps 128 VGPR < acc's 128. 256^2 tile
//   with 8 waves REQUIRES 1 block/CU.)
// v7 = m201-faithful: BK=64, dbuf, 4 phases/K-tile {16/0/8/0 ds_reads, 16
// MFMA each}, B in regs whole tile, A-half reused 2 phases, stage-into-
// CURRENT-buffer stagger (B after ph1 -> staged ph2; A after ph3 -> ph4),
// vmcnt(8) once per K-tile (waits loads issued >=4 phases back), base+imm
// ds_read offsets (2 base regs, compile-time offsets).

typedef __bf16 bf16;
typedef __bf16 bf16x8 __attribute__((ext_vector_type(8)));
typedef float f32x4 __attribute__((ext_vector_type(4)));

#define KE 4160
#define NN 4096
#define MM 4096
#define BB 8192

// ---------------- prep: build R_cat (bf16) and L columns of Wq ----------------
__global__ void prep_kernel(const float* __restrict__ Lft, const float* __restrict__ Rft,
                            const float* __restrict__ Lres, const float* __restrict__ Rres,
                            bf16* __restrict__ Rcat, bf16* __restrict__ Wq) {
  int tid = blockIdx.x * 256 + threadIdx.x;   // 524288 total
  if (tid < 64 * 4096) {
    int r = tid >> 12, n = tid & 4095;
    float v = (r < 48) ? Rres[r * 4096 + n] : Rft[(r - 48) * 4096 + n];
    Rcat[tid] = (bf16)v;
  } else {
    int t2 = tid - 64 * 4096;
    int m = t2 >> 6, r = t2 & 63;
    float v = (r < 48) ? Lres[m * 48 + r] : Lft[m * 16 + (r - 48)];
    Wq[(size_t)m * KE + 4096 + r] = (bf16)v;
  }
}

// ---------------- decode: Wq[:, :4096] = bf16(0.02*grid[Q_idxs]) ----------------
__global__ void decode_kernel(const int* __restrict__ qidx, const float* __restrict__ grid,
                              bf16* __restrict__ Wq) {
  int tid = blockIdx.x * 256 + threadIdx.x;   // 4096*512 = 2M
  int m = tid >> 9, g = tid & 511;
  uint32_t idx = (uint32_t)qidx[tid];
  const float4* gp = (const float4*)(grid + (size_t)idx * 8);
  float4 w0 = gp[0], w1 = gp[1];
  bf16x8 o;
  o[0] = (bf16)(w0.x * 0.02f); o[1] = (bf16)(w0.y * 0.02f);
  o[2] = (bf16)(w0.z * 0.02f); o[3] = (bf16)(w0.w * 0.02f);
  o[4] = (bf16)(w1.x * 0.02f); o[5] = (bf16)(w1.y * 0.02f);
  o[6] = (bf16)(w1.z * 0.02f); o[7] = (bf16)(w1.w * 0.02f);
  *(bf16x8*)(Wq + (size_t)m * KE + g * 8) = o;
}

// 4-stage (16-point) FWHT on a register array
#define FWHT16(v) \
  _Pragma("unroll") \
  for (int s_ = 1; s_ < 16; s_ <<= 1) { \
    _Pragma("unroll") \
    for (int i_ = 0; i_ < 16; ++i_) { \
      if (!(i_ & s_)) { float a_ = v[i_], b_ = v[i_ + s_]; v[i_] = a_ + b_; v[i_ + s_] = a_ - b_; } \
    } \
  }

// ---------------- FWHT-4096 radix-16 3-pass, f32 in -> bf16 out ----------------
__global__ void fwht_pre_kernel(const float* __restrict__ src,
                                bf16* __restrict__ dst,
                                const float* __restrict__ SU) {
  __shared__ float buf[4352];
  const int row = blockIdx.x, t = threadIdx.x;
  const float4* sp = (const float4*)(src + (size_t)row * NN + t * 16);
  const float4* su = (const float4*)(SU + t * 16);
  float v[16];
#pragma unroll
  for (int q = 0; q < 4; ++q) {
    float4 a = sp[q], s = su[q];
    v[q * 4 + 0] = a.x * s.x; v[q * 4 + 1] = a.y * s.y;
    v[q * 4 + 2] = a.z * s.z; v[q * 4 + 3] = a.w * s.w;
  }
  FWHT16(v)
#pragma unroll
  for (int i = 0; i < 16; ++i) buf[17 * t + i] = v[i];
  __syncthreads();
  const int base = ((t >> 4) << 8) | (t & 15);
#pragma unroll
  for (int k = 0; k < 16; ++k) { int a = base + (k << 4); v[k] = buf[a + (a >> 4)]; }
  FWHT16(v)
#pragma unroll
  for (int k = 0; k < 16; ++k) { int a = base + (k << 4); buf[a + (a >> 4)] = v[k]; }
  __syncthreads();
#pragma unroll
  for (int k = 0; k < 16; ++k) { int a = t + (k << 8); v[k] = buf[a + (a >> 4)]; }
  FWHT16(v)
  bf16* dp = dst + (size_t)row * KE;
#pragma unroll
  for (int k = 0; k < 16; ++k) dp[t + (k << 8)] = (bf16)(v[k] * 0.015625f);
}

// ---------------- FWHT-4096 radix-16 3-pass, f32 in-place (post, *SV) ----------------
__global__ void fwht_post_kernel(float* __restrict__ data, const float* __restrict__ SV) {
  __shared__ float buf[4352];
  const int row = blockIdx.x, t = threadIdx.x;
  const float4* dp = (const float4*)(data + (size_t)row * MM + t * 16);
  float v[16];
#pragma unroll
  for (int q = 0; q < 4; ++q) {
    float4 a = dp[q];
    v[q * 4 + 0] = a.x; v[q * 4 + 1] = a.y; v[q * 4 + 2] = a.z; v[q * 4 + 3] = a.w;
  }
  FWHT16(v)
#pragma unroll
  for (int i = 0; i < 16; ++i) buf[17 * t + i] = v[i];
  __syncthreads();
  const int base = ((t >> 4) << 8) | (t & 15);
#pragma unroll
  for (int k = 0; k < 16; ++k) { int a = base + (k << 4); v[k] = buf[a + (a >> 4)]; }
  FWHT16(v)
#pragma unroll
  for (int k = 0; k < 16; ++k) { int a = base + (k << 4); buf[a + (a >> 4)] = v[k]; }
  __syncthreads();
#pragma unroll
  for (int k = 0; k < 16; ++k) { int a = t + (k << 8); v[k] = buf[a + (a >> 4)]; }
  FWHT16(v)
  float* op = data + (size_t)row * MM;
#pragma unroll
  for (int k = 0; k < 16; ++k) { int a = t + (k << 8); op[a] = v[k] * 0.015625f * SV[a]; }
}

// ---------------- tgemm: Tpart[split] = h @ R_cat^T ----------------
__global__ void __launch_bounds__(256) tgemm_kernel(const bf16* __restrict__ A,
                                                    const bf16* __restrict__ Bm,
                                                    float* __restrict__ Tpart) {
  __shared__ bf16 lA[128 * 32];
  __shared__ bf16 lB[64 * 32];
  const int t = threadIdx.x, w = t >> 6, l = t & 63;
  const int bmBlk = blockIdx.x;
  const int split = blockIdx.y;
  const int wm = w >> 1, wn = w & 1;
  f32x4 acc[4][2] = {};
  const int arow = t >> 1, acol = (t & 1) * 16;
  const bf16* pa = A + (size_t)(bmBlk * 128 + arow) * KE + acol;
  const int brow = (t & 127) >> 1, bcol = acol;
  const bf16* pb = Bm + (size_t)brow * 4096 + bcol;
  const int fr = l & 15, fk = (l >> 4) * 8;
  for (int kt = 0; kt < 32; ++kt) {
    const int k0 = (split * 32 + kt) * 32;
    bf16x8 a0 = *(const bf16x8*)(pa + k0);
    bf16x8 a1 = *(const bf16x8*)(pa + k0 + 8);
    *(bf16x8*)&lA[arow * 32 + acol] = a0;
    *(bf16x8*)&lA[arow * 32 + acol + 8] = a1;
    if (t < 128) {
      bf16x8 b0 = *(const bf16x8*)(pb + k0);
      bf16x8 b1 = *(const bf16x8*)(pb + k0 + 8);
      *(bf16x8*)&lB[brow * 32 + bcol] = b0;
      *(bf16x8*)&lB[brow * 32 + bcol + 8] = b1;
    }
    __syncthreads();
    bf16x8 af[4], bfr[2];
#pragma unroll
    for (int i = 0; i < 4; ++i) af[i] = *(const bf16x8*)&lA[(wm * 64 + i * 16 + fr) * 32 + fk];
#pragma unroll
    for (int i = 0; i < 2; ++i) bfr[i] = *(const bf16x8*)&lB[(wn * 32 + i * 16 + fr) * 32 + fk];
#pragma unroll
    for (int mi = 0; mi < 4; ++mi)
#pragma unroll
      for (int ni = 0; ni < 2; ++ni)
        acc[mi][ni] = __builtin_amdgcn_mfma_f32_16x16x32_bf16(af[mi], bfr[ni], acc[mi][ni], 0, 0, 0);
    __syncthreads();
  }
  float* out = Tpart + (size_t)split * BB * 64;
  const int orow = bmBlk * 128 + wm * 64 + (l >> 4) * 4;
  const int ocol = wn * 32 + (l & 15);
#pragma unroll
  for (int mi = 0; mi < 4; ++mi)
#pragma unroll
    for (int ni = 0; ni < 2; ++ni)
#pragma unroll
      for (int r = 0; r < 4; ++r)
        out[(size_t)(orow + mi * 16 + r) * 64 + ocol + ni * 16] = acc[mi][ni][r];
}

__global__ void tconv_kernel(const float* __restrict__ Tpart, bf16* __restrict__ h) {
  int i = blockIdx.x * 256 + threadIdx.x;
  float s = Tpart[i] + Tpart[i + BB * 64] + Tpart[i + 2 * BB * 64] + Tpart[i + 3 * BB * 64];
  int row = i >> 6, c = i & 63;
  h[(size_t)row * KE + 4096 + c] = (bf16)s;
}

// ---------------- mgemm v7: 256^2, BK=64, double-buffer, 4-phase/K-tile ----------------
// C[8192,4096] f32 = A[8192,4160] @ B[4096,4160]^T, bf16 MFMA.
// LDS 128 KiB: buf b at b*65536: A tile 256x64 bf16 [0,32768), B [32768,65536).
// Swizzle (within a 128 B row): col ^= (row&7)<<4  -> frag ds_read 2-way max.
// Applied to gload SOURCE (LDS dest linear) and folded into ds_read immediates
// (row&7 == l&7 for all frags -> 2 per-lane constants c0/c1).
// Per K-tile t (buffer b = t&1), 4 phases {work; bar; 16 MFMA; bar}:
//  ph1: rd A-lo 8 + B 8 (lgkmcnt(8));       MFMA acc[0..3][0..1]
//  ph2: stage (t+2).B (4 gloads);           MFMA acc[0..3][2..3]   (B regs reused)
//  ph3: rd A-hi 8;                          MFMA acc[4..7][0..1]
//  ph4: stage (t+2).A (4 gloads); vmcnt;    MFMA acc[4..7][2..3]   (A-hi reused)
// Stagger legality: B region last read ph1 -> staged ph2; A last read ph3 ->
// staged ph4 (end-of-phase barriers separate). vmcnt(8) at end ph4 leaves
// (t+2)'s 8 loads outstanding, retires (t+1)'s -> landed block-wide after bar;
// waited loads were issued >=4 phases (~2500cyc) back. Tail: t=63 vmcnt(0)
// (loads 6+ phases old), t=64 none.

__device__ __forceinline__ void gload16(const void* g, void* l) {
  __builtin_amdgcn_global_load_lds(
      (const __attribute__((address_space(1))) void*)g,
      (__attribute__((address_space(3))) void*)l, 16, 0, 0);
}

__device__ __forceinline__ void bar() {
  asm volatile("" ::: "memory");
  __builtin_amdgcn_s_barrier();
  asm volatile("" ::: "memory");
}

#define MFMA16(mb, nb) \
  __builtin_amdgcn_s_setprio(1); \
  _Pragma("unroll") \
  for (int mi = 0; mi < 4; ++mi) \
    _Pragma("unroll") \
    for (int nf = 0; nf < 2; ++nf) \
      _Pragma("unroll") \
      for (int ks = 0; ks < 2; ++ks) \
        acc[(mb) + mi][(nb) + nf] = __builtin_amdgcn_mfma_f32_16x16x32_bf16( \
            af[mi * 2 + ks], bv[((nb) + nf) * 2 + ks], acc[(mb) + mi][(nb) + nf], 0, 0, 0); \
  __builtin_amdgcn_s_setprio(0);

__global__ void __launch_bounds__(512, 2) mgemm_kernel(const bf16* __restrict__ A,
                                                       const bf16* __restrict__ B,
                                                       float* __restrict__ C) {
  __shared__ alignas(16) char lds[131072];
  const int t = threadIdx.x;
  const int w = t >> 6, l = t & 63;
  const int wm = w >> 2, wn = w & 3;           // 2M x 4N waves, per-wave 128x64
  // bijective XCD swizzle (512 blocks, 512%8==0)
  const int bid = blockIdx.x;
  const int swzb = (bid & 7) * 64 + (bid >> 3);
  const int bm = swzb >> 4, bn = swzb & 15;    // 32 x 16 tiles

  // ---- staging: 8 (mat,half,g) units; thread covers linear half-tile byte
  // lb = g*8192 + t*16; logical row = h*128 + lb>>7, colb = lb&127;
  // source col pre-swizzled so linear LDS + swizzled ds_read agree.
  const char* gA[4]; const char* gB[4]; int dstA[4], dstB[4];
#pragma unroll
  for (int hg = 0; hg < 4; ++hg) {
    int h = hg >> 1, g = hg & 1;
    int lb = g * 8192 + t * 16;
    int row = h * 128 + (lb >> 7);
    int colb = lb & 127;
    int scol = colb ^ ((row & 7) << 4);
    gA[hg] = (const char*)A + (size_t)(bm * 256 + row) * (KE * 2) + scol;
    gB[hg] = (const char*)B + (size_t)(bn * 256 + row) * (KE * 2) + scol;
    dstA[hg] = h * 16384 + g * 8192 + w * 1024;            // wave-uniform base
    dstB[hg] = 32768 + h * 16384 + g * 8192 + w * 1024;
  }

  // ---- fragment read bases: row&7 == l&7 for every frag -> single XOR const
  const int fr = l & 15, q = l >> 4;
  const int X = (l & 7) << 4;
  const int c0 = (q * 16) ^ X;                 // ks=0 column byte (swizzled)
  const int c1 = (64 | (q * 16)) ^ X;          // ks=1
  const int rA = (wm * 128 + fr) * 128;        // A frag row base (byte)
  const int rB = 32768 + (wn * 64 + fr) * 128; // B frag row base (byte)

  f32x4 acc[8][4] = {};

  // ---- prologue: stage tiles 0,1 (16 gloads); vmcnt(8) -> tile 0 landed
#pragma unroll
  for (int p = 0; p < 2; ++p) {
#pragma unroll
    for (int hg = 0; hg < 4; ++hg) gload16(gA[hg] + p * 128, &lds[p * 65536 + dstA[hg]]);
#pragma unroll
    for (int hg = 0; hg < 4; ++hg) gload16(gB[hg] + p * 128, &lds[p * 65536 + dstB[hg]]);
  }
  asm volatile("s_waitcnt vmcnt(8)" ::: "memory");
  bar();

  // ---- main loop: 65 K-tiles of 64
  for (int kt = 0; kt < 65; ++kt) {
    const int buf = (kt & 1) << 16;
    const size_t ko = (size_t)(kt + 2) << 7;   // stage tile kt+2 (same buffer)
    const int bA = buf + rA, bB = buf + rB;
    bf16x8 af[8], bv[8];

    // ph1: A-lo (mi 0-3) + all B
#pragma unroll
    for (int f = 0; f < 8; ++f) af[f] = *(const bf16x8*)&lds[bA + ((f >> 1) << 11) + ((f & 1) ? c1 : c0)];
#pragma unroll
    for (int f = 0; f < 8; ++f) bv[f] = *(const bf16x8*)&lds[bB + ((f >> 1) << 11) + ((f & 1) ? c1 : c0)];
    asm volatile("s_waitcnt lgkmcnt(8)" ::: "memory");
    bar();
    MFMA16(0, 0)
    bar();

    // ph2: stage (kt+2).B; MFMA with reused af, bv[n2-3]
    if (kt <= 62) {
#pragma unroll
      for (int hg = 0; hg < 4; ++hg) gload16(gB[hg] + ko, &lds[buf + dstB[hg]]);
    }
    bar();
    MFMA16(0, 2)
    bar();

    // ph3: A-hi (mi 4-7)
#pragma unroll
    for (int f = 0; f < 8; ++f) af[f] = *(const bf16x8*)&lds[bA + 8192 + ((f >> 1) << 11) + ((f & 1) ? c1 : c0)];
    bar();
    MFMA16(4, 0)
    bar();

    // ph4: stage (kt+2).A; MFMA; counted vmcnt
    if (kt <= 62) {
#pragma unroll
      for (int hg = 0; hg < 4; ++hg) gload16(gA[hg] + ko, &lds[buf + dstA[hg]]);
    }
    bar();
    MFMA16(4, 2)
    if (kt <= 62) {
      asm volatile("s_waitcnt vmcnt(8)" ::: "memory");   // tile kt+1 landed
    } else if (kt == 63) {
      asm volatile("s_waitcnt vmcnt(0)" ::: "memory");   // tile 64 landed
    }
    bar();
  }

  // ---- epilogue: C write (verified lane->C mapping)
  const int orow = bm * 256 + wm * 128 + ((l >> 4) << 2);
  const int ocol = bn * 256 + wn * 64 + (l & 15);
#pragma unroll
  for (int mi = 0; mi < 8; ++mi)
#pragma unroll
    for (int ni = 0; ni < 4; ++ni)
#pragma unroll
      for (int r = 0; r < 4; ++r)
        C[(size_t)(orow + mi * 16 + r) * MM + ocol + ni * 16] = acc[mi][ni][r];
}

extern "C" void kernel_launch(void* const* d_in, const int* in_sizes, int n_in,
                              void* d_out, int out_size, void* d_ws, size_t ws_size,
                              hipStream_t stream) {
  const float* x    = (const float*)d_in[0];
  const float* SU   = (const float*)d_in[1];
  const float* SV   = (const float*)d_in[2];
  const float* grid = (const float*)d_in[3];
  const float* Lft  = (const float*)d_in[4];
  const float* Rft  = (const float*)d_in[5];
  const float* Lres = (const float*)d_in[6];
  const float* Rres = (const float*)d_in[7];
  const int*   qidx = (const int*)d_in[10];
  float* out = (float*)d_out;

  char* ws = (char*)d_ws;
  bf16*  h     = (bf16*)ws;                                   // 8192*4160*2 = 68,157,440
  bf16*  Wq    = (bf16*)(ws + 68157440);                      // 4096*4160*2 = 34,078,720
  bf16*  Rcat  = (bf16*)(ws + 68157440 + 34078720);           // 64*4096*2   =    524,288
  float* Tpart = (float*)(ws + 68157440 + 34078720 + 524288); // 4*8192*64*4 =  8,388,608

  prep_kernel<<<2048, 256, 0, stream>>>(Lft, Rft, Lres, Rres, Rcat, Wq);
  decode_kernel<<<8192, 256, 0, stream>>>(qidx, grid, Wq);
  fwht_pre_kernel<<<8192, 256, 0, stream>>>(x, h, SU);
  tgemm_kernel<<<dim3(64, 4), 256, 0, stream>>>(h, Rcat, Tpart);
  tconv_kernel<<<2048, 256, 0, stream>>>(Tpart, h);
  mgemm_kernel<<<512, 512, 0, stream>>>(h, Wq, out);
  fwht_post_kernel<<<8192, 256, 0, stream>>>(out, SV);
}